// Round 3
// baseline (286.864 us; speedup 1.0000x reference)
//
#include <hip/hip_runtime.h>
#include <stdint.h>

#define DM 1024
#define DK 128
#define SEQ 4096
#define NB 4
#define NSPLIT 4
#define KSPAN (SEQ / NSPLIT)
#define NQT (SEQ / 128)

typedef float f32x4 __attribute__((ext_vector_type(4)));
typedef float f32x16 __attribute__((ext_vector_type(16)));
typedef __bf16 bf16x8 __attribute__((ext_vector_type(8)));
typedef unsigned short u16x8 __attribute__((ext_vector_type(8)));
typedef unsigned short u16x4 __attribute__((ext_vector_type(4)));

__device__ __forceinline__ unsigned short f2bf(float f) {
    unsigned int u = __builtin_bit_cast(unsigned int, f);
    u += 0x7fffu + ((u >> 16) & 1u);
    return (unsigned short)(u >> 16);
}
__device__ __forceinline__ float bf2f(unsigned short h) {
    unsigned int u = ((unsigned int)h) << 16;
    return __builtin_bit_cast(float, u);
}
__device__ __forceinline__ f32x4 mfma16(u16x8 a, u16x8 b, f32x4 c) {
    return __builtin_amdgcn_mfma_f32_16x16x32_bf16(
        __builtin_bit_cast(bf16x8, a), __builtin_bit_cast(bf16x8, b), c, 0, 0, 0);
}
__device__ __forceinline__ f32x16 mfma32(u16x8 a, u16x8 b, f32x16 c) {
    return __builtin_amdgcn_mfma_f32_32x32x16_bf16(
        __builtin_bit_cast(bf16x8, a), __builtin_bit_cast(bf16x8, b), c, 0, 0, 0);
}

// fp32 pair -> bf16x8 (compiler emits v_cvt_pk_bf16_f32 pairs, RNE — same
// rounding as f2bf).
__device__ __forceinline__ bf16x8 cvt84(f32x4 lo, f32x4 hi) {
    bf16x8 r;
    r[0] = (__bf16)lo[0]; r[1] = (__bf16)lo[1]; r[2] = (__bf16)lo[2]; r[3] = (__bf16)lo[3];
    r[4] = (__bf16)hi[0]; r[5] = (__bf16)hi[1]; r[6] = (__bf16)hi[2]; r[7] = (__bf16)hi[3];
    return r;
}

// global -> LDS direct copy, 16B per lane. LDS dest is wave-uniform base +
// lane*16 (hardware rule); generic->AS3 via uintptr (CK pattern: low 32 bits
// of a flat shared address are the LDS offset).
__device__ __forceinline__ void gll16(const void* g, void* l) {
    __builtin_amdgcn_global_load_lds(
        (const __attribute__((address_space(1))) unsigned int*)(uintptr_t)g,
        (__attribute__((address_space(3))) unsigned int*)(uintptr_t)l,
        16, 0, 0);
}

// ---------------- Kernel A: wT[mat][d][k] = w[mat][k][d] (fp32 -> bf16) -----
__global__ __launch_bounds__(256) void wt_kernel(
        const float* __restrict__ wq, const float* __restrict__ wk,
        const float* __restrict__ wv, unsigned short* __restrict__ wT) {
    __shared__ unsigned short T[64 * 72];
    const int kt = blockIdx.x, dt = blockIdx.y, mat = blockIdx.z;
    const float* src = (mat == 0) ? wq : (mat == 1 ? wk : wv);
    const int tid = threadIdx.x;
    const int rb = tid >> 4, c4 = (tid & 15) * 4;
    float4 x[4];
#pragma unroll
    for (int i = 0; i < 4; i++)
        x[i] = *(const float4*)&src[(size_t)(kt * 64 + i * 16 + rb) * DK + dt * 64 + c4];
#pragma unroll
    for (int i = 0; i < 4; i++) {
        const int row = i * 16 + rb;
        T[(c4 + 0) * 72 + row] = f2bf(x[i].x);
        T[(c4 + 1) * 72 + row] = f2bf(x[i].y);
        T[(c4 + 2) * 72 + row] = f2bf(x[i].z);
        T[(c4 + 3) * 72 + row] = f2bf(x[i].w);
    }
    __syncthreads();
    const int dl = tid >> 2, ks0 = (tid & 3) * 16;
    unsigned short* dst = wT + (size_t)mat * DM * DK + (size_t)(dt * 64 + dl) * DM + kt * 64 + ks0;
#pragma unroll
    for (int j = 0; j < 2; j++)
        *(u16x8*)&dst[8 * j] = *(const u16x8*)&T[dl * 72 + ks0 + 8 * j];
}

// ---------------- Kernel B: merged projections, global_load_lds, BK=64 -----
// R7: reg-prefetch failed (VGPR=80 => loads sunk into MFMA section =>
// latency-serialized: MfmaUtil 6%, HBM 19%). Replaced with m97 structure:
// global_load_lds(16B) staging, single 32KB LDS buffer, 2 barriers/K-step.
// 3 blocks/CU overlap the per-block vmcnt drain. LDS is linear (gll writes
// lane*16B from uniform base; no padding possible), so bank conflicts are
// avoided T2-style: XOR-swizzled source address + same XOR on ds_read.
//   Xs fp32 [64][64]: 32B chunk c at phys (c^(row&7)), 16B half h at (h^row.bit3)
//   Ws bf16 [128][64]: 16B chunk c at phys (c^(row&7))
// => every quarter-wave fragment read lands 2 lanes/bank (free, m136).
__global__ __launch_bounds__(256)
void proj_kernel(
        const float* __restrict__ qin, const float* __restrict__ kin,
        const float* __restrict__ vin, const unsigned short* __restrict__ wT,
        const float* __restrict__ bq, const float* __restrict__ bk,
        const float* __restrict__ bv,
        unsigned short* __restrict__ qp, unsigned short* __restrict__ kp,
        unsigned short* __restrict__ vpT) {
    __shared__ __align__(16) char smem[64 * 64 * 4 + 128 * 64 * 2];  // 32 KB
    float* Xs = (float*)smem;                                    // [64][64] fp32
    unsigned short* Ws = (unsigned short*)(smem + 64 * 64 * 4);  // [128][64] bf16

    const int y = blockIdx.y;
    const float* X = (y == 0) ? qin : (y == 1 ? kin : vin);
    const unsigned short* WTm = wT + (size_t)y * (DM * DK);
    const float* bias = (y == 0) ? bq : (y == 1 ? bk : bv);

    const int tid = threadIdx.x;
    const int w = tid >> 6, lane = tid & 63, l16 = lane & 15, quad = lane >> 4;
    const int t0 = blockIdx.x * 64;

    // ---- staging pointers (pre-swizzled global source, linear LDS dest) ----
    const int lr4 = lane >> 4, h16 = lane & 15;  // X: 4 rows/KB-issue, 16B slots
    const int lr8 = lane >> 3, h8 = lane & 7;    // W: 8 rows/KB-issue, 16B slots
    const float* xsrc[4];
    const unsigned short* wsrc[4];
    float* xdst[4];
    unsigned short* wdst[4];
#pragma unroll
    for (int i = 0; i < 4; i++) {
        const int xrow = w * 16 + i * 4 + lr4;  // 0..63
        const int xcol = (((h16 >> 1) ^ (xrow & 7)) << 3) |
                         (((h16 & 1) ^ ((xrow >> 3) & 1)) << 2);
        xsrc[i] = X + (size_t)(t0 + xrow) * DM + xcol;
        xdst[i] = Xs + (w * 16 + i * 4) * 64;   // wave-uniform
        const int wrow = w * 32 + i * 8 + lr8;  // 0..127 ; wrow&7 == lr8
        const int wcol = (h8 ^ lr8) << 3;
        wsrc[i] = WTm + (size_t)wrow * DM + wcol;
        wdst[i] = Ws + (w * 32 + i * 8) * 64;   // wave-uniform
    }

    f32x4 zero = {0.f, 0.f, 0.f, 0.f};
    f32x4 acc[4][2];
#pragma unroll
    for (int mf = 0; mf < 4; mf++)
#pragma unroll
        for (int nf = 0; nf < 2; nf++) acc[mf][nf] = zero;

    // prologue: stage K-step 0
#pragma unroll
    for (int i = 0; i < 4; i++) { gll16(xsrc[i], xdst[i]); gll16(wsrc[i], wdst[i]); }

    const int swz = l16 & 7, h3 = (l16 >> 3) & 1;
    for (int t = 0; t < 16; ++t) {
        __syncthreads();  // compiler drains vmcnt(0) before s_barrier: tile visible
#pragma unroll
        for (int ks = 0; ks < 2; ks++) {
            const int ca = ((ks << 2) | quad) ^ swz;  // shared chunk swizzle (A & B)
            bf16x8 av[4];
            u16x8 bvf[2];
#pragma unroll
            for (int mf = 0; mf < 4; mf++) {
                const float* ap = &Xs[(l16 + 16 * mf) * 64 + ca * 8];
                f32x4 lo = *(const f32x4*)(ap + 4 * h3);        // logical half0
                f32x4 hi = *(const f32x4*)(ap + 4 * (h3 ^ 1));  // logical half1
                av[mf] = cvt84(lo, hi);
            }
#pragma unroll
            for (int nf = 0; nf < 2; nf++)
                bvf[nf] = *(const u16x8*)&Ws[(32 * w + 16 * nf + l16) * 64 + ca * 8];
#pragma unroll
            for (int mf = 0; mf < 4; mf++)
#pragma unroll
                for (int nf = 0; nf < 2; nf++)
                    acc[mf][nf] = __builtin_amdgcn_mfma_f32_16x16x32_bf16(
                        av[mf], __builtin_bit_cast(bf16x8, bvf[nf]), acc[mf][nf], 0, 0, 0);
        }
        __syncthreads();  // all waves done reading before overwrite
        if (t < 15) {
#pragma unroll
            for (int i = 0; i < 4; i++) {
                xsrc[i] += 64;  // next 64 fp32 along K
                wsrc[i] += 64;  // next 64 bf16 along K
                gll16(xsrc[i], xdst[i]);
                gll16(wsrc[i], wdst[i]);
            }
        }
    }

    if (y < 2) {
        unsigned short* outp = y ? kp : qp;
#pragma unroll
        for (int nf = 0; nf < 2; nf++) {
            const int n = l16 + 32 * w + 16 * nf;
            const float bb = bias[n];
#pragma unroll
            for (int mf = 0; mf < 4; mf++)
#pragma unroll
                for (int r = 0; r < 4; r++)
                    outp[(size_t)(t0 + 16 * mf + quad * 4 + r) * DK + n] = f2bf(acc[mf][nf][r] + bb);
        }
    } else {
        __syncthreads();
        unsigned short* Tb = (unsigned short*)smem;  // 18 KB overlay, loop is done
#pragma unroll
        for (int nf = 0; nf < 2; nf++) {
            const int d = l16 + 32 * w + 16 * nf;
            const float bb = bias[d];
#pragma unroll
            for (int mf = 0; mf < 4; mf++)
#pragma unroll
                for (int r = 0; r < 4; r++)
                    Tb[d * 72 + 16 * mf + quad * 4 + r] = f2bf(acc[mf][nf][r] + bb);
        }
        __syncthreads();
        const int d2 = tid >> 1, ts = (tid & 1) * 32;
        const int b2 = t0 >> 12, tl0 = t0 & (SEQ - 1);
#pragma unroll
        for (int j = 0; j < 4; j++)
            *(u16x8*)&vpT[((size_t)(b2 * DK + d2)) * SEQ + tl0 + ts + 8 * j] =
                *(const u16x8*)&Tb[d2 * 72 + ts + 8 * j];
    }
}

// ---------------- Kernel C: flash attention partials -----------------------
// waves_per_eu(2,2): grid 512 = exactly 2 blocks/CU; raise VGPR budget to 256
// so kbuf/vbuf prefetch stays live across the MFMA section.
__global__ __launch_bounds__(256)
__attribute__((amdgpu_waves_per_eu(2, 2)))
void attn_part_kernel(
        const unsigned short* __restrict__ qp, const unsigned short* __restrict__ kp,
        const unsigned short* __restrict__ vpT,
        unsigned short* __restrict__ Opart, float* __restrict__ Lw) {
    __shared__ unsigned short Ks[64 * 136];  // [key][d]
    __shared__ unsigned short Vs[128 * 72];  // [d][key]

    const int tid = threadIdx.x;
    const int w = tid >> 6, lane = tid & 63, l32 = lane & 31, h = lane >> 5;
    const int qt = blockIdx.x, pi = blockIdx.y, b = blockIdx.z;
    const int q0 = qt * 128;
    const int kbase = pi * KSPAN;
    const float csc = 0.08838834764831845f * 1.4426950408889634f;  // scale*log2(e)

    u16x8 qf[8];
    {
        const unsigned short* qrow = qp + (size_t)(b * SEQ + q0 + 32 * w + l32) * DK + 8 * h;
#pragma unroll
        for (int c = 0; c < 8; c++) qf[c] = *(const u16x8*)&qrow[16 * c];
    }

    f32x16 oacc[4];
#pragma unroll
    for (int i = 0; i < 4; i++)
#pragma unroll
        for (int j = 0; j < 16; j++) oacc[i][j] = 0.f;
    float l_acc = 0.f;

    const int krow = tid >> 2, kch = (tid & 3) * 8;
    const int vrow = tid >> 1, voff = (tid & 1) * 8;
    uint4 kbuf[4], vbuf[4];
    {
        const unsigned short* kg = kp + (size_t)(b * SEQ + kbase + krow) * DK + kch;
        const unsigned short* vg = vpT + (size_t)(b * DK + vrow) * SEQ + kbase + voff;
#pragma unroll
        for (int i = 0; i < 4; i++) {
            kbuf[i] = *(const uint4*)&kg[32 * i];
            vbuf[i] = *(const uint4*)&vg[16 * i];
        }
    }

    for (int it = 0; it < KSPAN / 64; it++) {
        __syncthreads();
#pragma unroll
        for (int i = 0; i < 4; i++) {
            *(u16x8*)&Ks[krow * 136 + kch + 32 * i] = __builtin_bit_cast(u16x8, kbuf[i]);
            *(u16x8*)&Vs[vrow * 72 + voff + 16 * i] = __builtin_bit_cast(u16x8, vbuf[i]);
        }
        __syncthreads();
        if (it + 1 < KSPAN / 64) {
            const int kn = kbase + (it + 1) * 64;
            const unsigned short* kg = kp + (size_t)(b * SEQ + kn + krow) * DK + kch;
            const unsigned short* vg = vpT + (size_t)(b * DK + vrow) * SEQ + kn + voff;
#pragma unroll
            for (int i = 0; i < 4; i++) {
                kbuf[i] = *(const uint4*)&kg[32 * i];
                vbuf[i] = *(const uint4*)&vg[16 * i];
            }
        }
        f32x16 sacc[2];
#pragma unroll
        for (int kb = 0; kb < 2; kb++)
#pragma unroll
            for (int j = 0; j < 16; j++) sacc[kb][j] = 0.f;
#pragma unroll
        for (int c = 0; c < 8; c++)
#pragma unroll
            for (int kb = 0; kb < 2; kb++) {
                u16x8 kf = *(const u16x8*)&Ks[(l32 + 32 * kb) * 136 + 16 * c + 8 * h];
                sacc[kb] = mfma32(kf, qf[c], sacc[kb]);
            }
        unsigned int pp[16];
#pragma unroll
        for (int kb = 0; kb < 2; kb++)
#pragma unroll
            for (int r2 = 0; r2 < 8; r2++) {
                float p0 = exp2f(sacc[kb][2 * r2] * csc);
                float p1 = exp2f(sacc[kb][2 * r2 + 1] * csc);
                l_acc += p0 + p1;
                pp[kb * 8 + r2] = (unsigned int)f2bf(p0) | ((unsigned int)f2bf(p1) << 16);
            }
#pragma unroll
        for (int c = 0; c < 4; c++) {
            const int bs = (c >> 1) * 8 + (c & 1) * 4;
            unsigned int o0 = pp[bs], o1 = pp[bs + 1], o2 = pp[bs + 2], o3 = pp[bs + 3];
            unsigned int x0 = __shfl_xor(o0, 32), x1 = __shfl_xor(o1, 32);
            unsigned int x2 = __shfl_xor(o2, 32), x3 = __shfl_xor(o3, 32);
            uint4 af;
            af.x = h ? x2 : o0;
            af.y = h ? x3 : o1;
            af.z = h ? o2 : x0;
            af.w = h ? o3 : x1;
            u16x8 afr = __builtin_bit_cast(u16x8, af);
#pragma unroll
            for (int db = 0; db < 4; db++) {
                u16x8 vf = *(const u16x8*)&Vs[(32 * db + l32) * 72 + 16 * c + 8 * h];
                oacc[db] = mfma32(afr, vf, oacc[db]);
            }
        }
    }
    float l_tot = l_acc + __shfl_xor(l_acc, 32);
    if (lane < 32)
        Lw[(size_t)(b * NSPLIT + pi) * SEQ + q0 + 32 * w + l32] = l_tot;
    float rl[16];
#pragma unroll
    for (int r = 0; r < 16; r++) {
        int qr = (r & 3) + 8 * (r >> 2) + 4 * h;
        rl[r] = 1.f / __shfl(l_tot, qr);
    }
    unsigned short* ob = Opart + ((size_t)((b * NSPLIT + pi) * NQT + qt)) * 16384 + (size_t)tid * 64;
#pragma unroll
    for (int db = 0; db < 4; db++) {
        u16x8 s0, s1;
#pragma unroll
        for (int j = 0; j < 8; j++) {
            s0[j] = f2bf(oacc[db][j] * rl[j]);
            s1[j] = f2bf(oacc[db][8 + j] * rl[8 + j]);
        }
        *(u16x8*)&ob[db * 16] = s0;
        *(u16x8*)&ob[db * 16 + 8] = s1;
    }
}

// ---------------- Kernel D: combine splits (d-split, 256 blocks) -----------
__global__ __launch_bounds__(256) void attn_combine_kernel(
        const unsigned short* __restrict__ Opart, const float* __restrict__ Lw,
        float* __restrict__ out) {
    __shared__ float Ls[NSPLIT * 128];
    const int tid = threadIdx.x;
    const int w = tid >> 6, lane = tid & 63, l32 = lane & 31, h = lane >> 5;
    const int qt = blockIdx.x, b = blockIdx.y, z = blockIdx.z;
    const int q0 = qt * 128;
    for (int i = tid; i < NSPLIT * 128; i += 256) {
        int pi = i >> 7, ql = i & 127;
        Ls[i] = Lw[(size_t)(b * NSPLIT + pi) * SEQ + q0 + ql];
    }
    __syncthreads();
    int qlr[16];
    float inv[16];
#pragma unroll
    for (int r = 0; r < 16; r++) {
        qlr[r] = 32 * w + (r & 3) + 8 * (r >> 2) + 4 * h;
        float s = 0.f;
#pragma unroll
        for (int pi = 0; pi < NSPLIT; pi++) s += Ls[pi * 128 + qlr[r]];
        inv[r] = 1.f / s;
    }
    float acc[32];
#pragma unroll
    for (int i = 0; i < 32; i++) acc[i] = 0.f;
#pragma unroll
    for (int pi = 0; pi < NSPLIT; pi++) {
        float wr[16];
#pragma unroll
        for (int r = 0; r < 16; r++) wr[r] = Ls[pi * 128 + qlr[r]] * inv[r];
        const unsigned short* ob =
            Opart + ((size_t)((b * NSPLIT + pi) * NQT + qt)) * 16384 + (size_t)tid * 64;
#pragma unroll
        for (int j = 0; j < 2; j++) {
            const int db = 2 * z + j;
#pragma unroll
            for (int hf = 0; hf < 2; hf++) {
                u16x8 v8 = *(const u16x8*)&ob[db * 16 + 8 * hf];
#pragma unroll
                for (int jj = 0; jj < 8; jj++)
                    acc[j * 16 + 8 * hf + jj] += wr[8 * hf + jj] * bf2f(v8[jj]);
            }
        }
    }
#pragma unroll
    for (int j = 0; j < 2; j++) {
        const int db = 2 * z + j;
#pragma unroll
        for (int r = 0; r < 16; r++)
            out[(size_t)(b * SEQ + q0 + qlr[r]) * DK + 32 * db + l32] = acc[j * 16 + r];
    }
}

extern "C" void kernel_launch(void* const* d_in, const int* in_sizes, int n_in,
                              void* d_out, int out_size, void* d_ws, size_t ws_size,
                              hipStream_t stream) {
    const float* q  = (const float*)d_in[0];
    const float* k  = (const float*)d_in[1];
    const float* v  = (const float*)d_in[2];
    const float* wq = (const float*)d_in[3];
    const float* bq = (const float*)d_in[4];
    const float* wk = (const float*)d_in[5];
    const float* bk = (const float*)d_in[6];
    const float* wv = (const float*)d_in[7];
    const float* bv = (const float*)d_in[8];
    float* out = (float*)d_out;

    char* ws = (char*)d_ws;
    unsigned short* wT    = (unsigned short*)(ws);                    // 768 KB
    unsigned short* qp    = (unsigned short*)(ws + (1u << 20));       // 4 MB
    unsigned short* kpb   = (unsigned short*)(ws + (5u << 20));       // 4 MB
    unsigned short* vpT   = (unsigned short*)(ws + (9u << 20));       // 4 MB
    unsigned short* Opart = (unsigned short*)(ws + (13u << 20));      // 16 MB
    float* Lw             = (float*)(ws + (29u << 20));               // 256 KB

    hipLaunchKernelGGL(wt_kernel, dim3(16, 2, 3), dim3(256), 0, stream, wq, wk, wv, wT);
    hipLaunchKernelGGL(proj_kernel, dim3(256, 3), dim3(256), 0, stream,
                       q, k, v, wT, bq, bk, bv, qp, kpb, vpT);
    hipLaunchKernelGGL(attn_part_kernel, dim3(NQT, NSPLIT, NB), dim3(256), 0, stream,
                       qp, kpb, vpT, Opart, Lw);
    hipLaunchKernelGGL(attn_combine_kernel, dim3(NQT, NB, 2), dim3(256), 0, stream,
                       Opart, Lw, out);
}